// Round 4
// baseline (4979.262 us; speedup 1.0000x reference)
//
#include <hip/hip_runtime.h>
#include <hip/hip_bf16.h>

#define SEQT 2000
#define NB   2048
#define H1   51
#define MROW 16
#define NBLK (NB / MROW)   // 128 blocks, 64 threads each: one wave owns 16 rows
#define PADK 168           // shorts per staged row (336 B = 21*16, 16B-aligned)
#define OSTR 65            // Obuf row stride (floats) — odd, conflict-free

typedef float f32x4 __attribute__((ext_vector_type(4)));
typedef short s16x8 __attribute__((ext_vector_type(8)));

__device__ __forceinline__ short f2bf(float f) { __hip_bfloat16 b(f); return *(short*)&b; }
__device__ __forceinline__ float bf2f(short s) { __hip_bfloat16 b; *(short*)&b = s; return (float)b; }
__device__ __forceinline__ float rbf(float f) { return bf2f(f2bf(f)); }
__device__ __forceinline__ float fastrcp(float x) { return __builtin_amdgcn_rcpf(x); }
__device__ __forceinline__ float sigf(float x) { return fastrcp(1.f + __expf(-x)); }
__device__ __forceinline__ float tanhfast(float x) { return 1.f - 2.f * fastrcp(__expf(2.f * x) + 1.f); }

// RNE f32->bf16 (bit trick; values are finite so no NaN path needed)
__device__ __forceinline__ unsigned rne_bf16(float v) {
    unsigned b = __float_as_uint(v);
    return (b + 0x7fffu + ((b >> 16) & 1u)) >> 16;
}
// packed (hi | lo<<16), both RNE — used off the hot path (x staging)
__device__ __forceinline__ unsigned pack_hilo(float v) {
    const unsigned hh = rne_bf16(v);
    const float hi = __uint_as_float(hh << 16);
    const unsigned hl = rne_bf16(v - hi);
    return hh | (hl << 16);
}

__device__ __forceinline__ f32x4 mfma16(s16x8 a, s16x8 b, f32x4 c) {
    return __builtin_amdgcn_mfma_f32_16x16x32_bf16(a, b, c, 0, 0, 0);
}

// SINGLE-WAVE-PER-BLOCK design: batch rows are independent, so one wave owns
// 16 rows end-to-end (all 13 N-tiles + LSTM3 + x + output). NO __syncthreads
// in the step loop — the h(ts) -> hf(ts+1) transpose goes through wave-private
// LDS, ordered by the wave's own in-order DS pipeline (lgkmcnt only).
//
// B-side (staged vector) column map, K=160 (5 k-tiles of 32):
//   2u/2u+1 (u<51): h_hi/h_lo      | A: Whh_hi[n][u] (both)
//   102+u   (u<51): h_hi           | A: Whh_lo[n][u]
//   153: x_hi  154: x_lo  155: x_hi| A: Wih_hi, Wih_hi, Wih_lo
//   156: 1.0   157: 1.0            | A: bias_hi, bias_lo
//   158,159: 0   160..167: write scratch (never read)
// Gate rows n' = u*4+g (13 N-tiles). MFMA A=weights, B=staged vector.
// C/D: col(lane&15)=m, row(quad*4+reg)=n' -> lane (kq,iloc) holds all 4 gates
// of unit u = tile*4+kq for batch row m = iloc.
// LSTM3 (H3=1): lane (kq,m) holds c1[u=4j+kq] in regs -> per-lane partial dots
// over W3T (LDS broadcast), 2x shfl_xor butterfly over kq (same association as
// the previous 4-chain sum -> bit-identical), finish on lanes 0..15.

// Fill one 64-step x-chunk into Xbuf (all 64 lanes).
__device__ __forceinline__ void xchunk_fill(const float* __restrict__ input, int r0, int c,
                                            int lane, unsigned (*Xb)[64 * 16]) {
    const int m = lane & 15, q = lane >> 4;
    const int tt = c * 64 + q * 16;
    f32x4 v[4];
    if (tt < SEQT) {
        const float* src = input + (size_t)(r0 + m) * SEQT + tt;
#pragma unroll
        for (int p = 0; p < 4; ++p) v[p] = *(const f32x4*)(src + 4 * p);
    } else {
#pragma unroll
        for (int p = 0; p < 4; ++p) v[p] = (f32x4){0.f, 0.f, 0.f, 0.f};
    }
#pragma unroll
    for (int p = 0; p < 4; ++p)
#pragma unroll
        for (int j = 0; j < 4; ++j)
            Xb[c & 1][(q * 16 + p * 4 + j) * 16 + m] = pack_hilo(v[p][j]);
}

__global__ void __launch_bounds__(64)
__attribute__((amdgpu_waves_per_eu(1)))
lstm_fused_kernel(const float* __restrict__ input,
                  const float* __restrict__ W_ih1,
                  const float* __restrict__ W_hh1,
                  const float* __restrict__ b_ih1,
                  const float* __restrict__ b_hh1,
                  const float* __restrict__ W_ih3,
                  const float* __restrict__ W_hh3,
                  const float* __restrict__ b_ih3,
                  const float* __restrict__ b_hh3,
                  float* __restrict__ out) {
    const int lane = threadIdx.x;      // 0..63, single wave
    const int iloc = lane & 15, kq = lane >> 4;
    const int r0 = blockIdx.x * MROW;

    __shared__ short Hst[MROW * PADK];         // staged h/x/bias rows (single buf)
    __shared__ float Obuf[2][MROW * OSTR];     // c3 chunks, parity dbuf
    __shared__ unsigned Xbuf[2][64 * 16];      // packed x hi/lo, 64-step chunks
    __shared__ float W3T[52 * 4];              // W_ih3 transposed: [u][g]

    // ---- gate-row weight fragments (A-operand), all 13 tiles in registers ----
    s16x8 Wfr[13][5];
#pragma unroll
    for (int i = 0; i < 13; ++i) {
        const int np = i * 16 + iloc;
        const int u = np >> 2, g = np & 3;
        const int n = g * H1 + u;
#pragma unroll
        for (int kt = 0; kt < 5; ++kt) {
            s16x8 bf;
#pragma unroll
            for (int j = 0; j < 8; ++j) {
                const int k = kt * 32 + kq * 8 + j;
                float v = 0.f;
                if (u < H1) {
                    if (k < 102) {
                        v = rbf(W_hh1[n * H1 + (k >> 1)]);
                    } else if (k < 153) {
                        const float wv = W_hh1[n * H1 + (k - 102)];
                        v = wv - rbf(wv);
                    } else if (k == 153 || k == 154) {
                        v = rbf(W_ih1[n]);
                    } else if (k == 155) {
                        const float wv = W_ih1[n];
                        v = wv - rbf(wv);
                    } else if (k == 156) {
                        v = rbf(b_ih1[n] + b_hh1[n]);
                    } else if (k == 157) {
                        const float bv = b_ih1[n] + b_hh1[n];
                        v = bv - rbf(bv);
                    }
                }
                bf[j] = f2bf(v);
            }
            Wfr[i][kt] = bf;
        }
    }

    // ---- LSTM3 constants ----
    const float whh3_0 = W_hh3[0], whh3_1 = W_hh3[1];
    const float whh3_2 = W_hh3[2], whh3_3 = W_hh3[3];
    const float b3_0 = b_ih3[0] + b_hh3[0];
    const float b3_1 = b_ih3[1] + b_hh3[1];
    const float b3_2 = b_ih3[2] + b_hh3[2];
    const float b3_3 = b_ih3[3] + b_hh3[3];
    // W3T[u*4+g] = W_ih3[g][u], zero-padded to u<52
    for (int idx = lane; idx < 208; idx += 64) {
        const int u = idx >> 2, g = idx & 3;
        W3T[idx] = (u < H1) ? W_ih3[g * H1 + u] : 0.f;
    }

    // ---- LDS init (single wave: program order + in-order DS, no barrier) ----
    for (int idx = lane; idx < MROW * PADK; idx += 64)
        Hst[idx] = 0;
    if (lane < MROW) {
        const int m = lane;
        Hst[m * PADK + 156] = (short)0x3F80;   // 1.0 (bias column)
        Hst[m * PADK + 157] = (short)0x3F80;
        const float x0 = input[(size_t)(r0 + m) * SEQT];
        const unsigned xp = pack_hilo(x0);
        Hst[m * PADK + 153] = (short)xp;
        Hst[m * PADK + 154] = (short)(xp >> 16);
        Hst[m * PADK + 155] = (short)xp;
    }
    xchunk_fill(input, r0, 0, lane, Xbuf);     // prefill x chunks 0 and 1
    xchunk_fill(input, r0, 1, lane, Xbuf);

    float c1st[13];
#pragma unroll
    for (int i = 0; i < 13; ++i) c1st[i] = 0.f;
    float h3 = 0.f, c3 = 0.f;                  // LSTM3 state (lanes 0..15)

#pragma unroll 1
    for (int ts = 0; ts < SEQT; ++ts) {
        // ---- B-frags: read h/x/bias of this step (written last step, in-order DS)
        s16x8 hf[5];
#pragma unroll
        for (int kt = 0; kt < 5; ++kt)
            hf[kt] = *(const s16x8*)&Hst[iloc * PADK + kt * 32 + kq * 8];

        // ---- coalesced dump of finished 64-chunk ----
        if (ts >= 65 && (ts & 63) == 1) {
            const int c = (ts >> 6) - 1;
#pragma unroll
            for (int row = 0; row < 16; ++row)
                out[(size_t)(r0 + row) * SEQT + c * 64 + lane] =
                    Obuf[c & 1][row * OSTR + lane];
        }

        // ---- x chunk prefetch: issue loads early (store at step bottom) ----
        const bool fill = ((ts & 63) == 0) && (ts >= 64) && ((ts >> 6) < 31);
        const int fc = (ts >> 6) + 1;
        f32x4 xv[4];
        if (fill) {
            const int fm = lane & 15, fq = lane >> 4;
            const int tt = fc * 64 + fq * 16;
            if (tt < SEQT) {
                const float* src = input + (size_t)(r0 + fm) * SEQT + tt;
#pragma unroll
                for (int p = 0; p < 4; ++p) xv[p] = *(const f32x4*)(src + 4 * p);
            } else {
#pragma unroll
                for (int p = 0; p < 4; ++p) xv[p] = (f32x4){0.f, 0.f, 0.f, 0.f};
            }
        }

        // ---- 13 N-tiles: MFMA + dense lane-local epilogue ----
#pragma unroll
        for (int i = 0; i < 13; ++i) {
            f32x4 a0 = (f32x4){0.f, 0.f, 0.f, 0.f};
            f32x4 a1 = (f32x4){0.f, 0.f, 0.f, 0.f};
            a0 = mfma16(Wfr[i][0], hf[0], a0);
            a1 = mfma16(Wfr[i][1], hf[1], a1);
            a0 = mfma16(Wfr[i][2], hf[2], a0);
            a1 = mfma16(Wfr[i][3], hf[3], a1);
            a0 = mfma16(Wfr[i][4], hf[4], a0);
            const f32x4 acc = a0 + a1;
            const int u = i * 4 + kq;
            float c1 = c1st[i];
            c1 = sigf(acc[1]) * c1 + sigf(acc[0]) * tanhfast(acc[2]);
            c1st[i] = c1;
            const float h1 = sigf(acc[3]) * tanhfast(c1);
            const bool ok = (u < H1);
            // RTZ hi + RNE lo (same combined 2^-17 error as RNE/RNE)
            const unsigned uv = __float_as_uint(h1);
            const unsigned hh = uv >> 16;
            const float hif = __uint_as_float(uv & 0xffff0000u);
            const unsigned ll = rne_bf16(h1 - hif);
            const unsigned hp = hh | (ll << 16);
            const int base = iloc * PADK;
            *(unsigned*)&Hst[base + (ok ? 2 * u : 160)] = hp;
            Hst[base + (ok ? 102 + u : 164)] = (short)hp;
        }

        // ---- x staging for step ts+1 (cols 153..155; hf already read above) ----
        {
            const int t1 = ts + 1;
            if (t1 < SEQT && lane < MROW) {
                const unsigned pv = Xbuf[(t1 >> 6) & 1][(t1 & 63) * 16 + iloc];
                Hst[iloc * PADK + 153] = (short)pv;
                Hst[iloc * PADK + 154] = (short)(pv >> 16);
                Hst[iloc * PADK + 155] = (short)pv;
            }
        }

        // ---- LSTM3(ts): in-register c1 dot + butterfly reduce over kq ----
        {
            float p0 = 0.f, p1 = 0.f, p2 = 0.f, p3 = 0.f;
#pragma unroll
            for (int j = 0; j < 13; ++j) {
                const f32x4 w3 = *(const f32x4*)&W3T[(4 * j + kq) * 4];
                p0 = fmaf(w3[0], c1st[j], p0);
                p1 = fmaf(w3[1], c1st[j], p1);
                p2 = fmaf(w3[2], c1st[j], p2);
                p3 = fmaf(w3[3], c1st[j], p3);
            }
            // (p(kq=0)+p(1)) + (p(2)+p(3)) — same association as before
            p0 += __shfl_xor(p0, 16, 64); p0 += __shfl_xor(p0, 32, 64);
            p1 += __shfl_xor(p1, 16, 64); p1 += __shfl_xor(p1, 32, 64);
            p2 += __shfl_xor(p2, 16, 64); p2 += __shfl_xor(p2, 32, 64);
            p3 += __shfl_xor(p3, 16, 64); p3 += __shfl_xor(p3, 32, 64);
            if (lane < MROW) {
                const float pi = p0 + fmaf(whh3_0, h3, b3_0);
                const float pf = p1 + fmaf(whh3_1, h3, b3_1);
                const float pg = p2 + fmaf(whh3_2, h3, b3_2);
                const float po = p3 + fmaf(whh3_3, h3, b3_3);
                c3 = sigf(pf) * c3 + sigf(pi) * tanhfast(pg);
                h3 = sigf(po) * tanhfast(c3);
                Obuf[(ts >> 6) & 1][lane * OSTR + (ts & 63)] = c3;
            }
        }

        // ---- x chunk prefetch: pack + store (loads had the step to land) ----
        if (fill) {
            const int fm = lane & 15, fq = lane >> 4;
#pragma unroll
            for (int p = 0; p < 4; ++p)
#pragma unroll
                for (int j = 0; j < 4; ++j)
                    Xbuf[fc & 1][(fq * 16 + p * 4 + j) * 16 + fm] =
                        pack_hilo(xv[p][j]);
        }
    }

    // tail: steps 1984..1999 (chunk 31, parity 1, 16 cols)
#pragma unroll
    for (int rep = 0; rep < 4; ++rep) {
        const int row = rep * 4 + kq;
        out[(size_t)(r0 + row) * SEQT + 1984 + iloc] = Obuf[1][row * OSTR + iloc];
    }
}

extern "C" void kernel_launch(void* const* d_in, const int* in_sizes, int n_in,
                              void* d_out, int out_size, void* d_ws, size_t ws_size,
                              hipStream_t stream) {
    const float* input = (const float*)d_in[0];
    const float* W_ih1 = (const float*)d_in[1];
    const float* W_hh1 = (const float*)d_in[2];
    const float* b_ih1 = (const float*)d_in[3];
    const float* b_hh1 = (const float*)d_in[4];
    const float* W_ih3 = (const float*)d_in[5];
    const float* W_hh3 = (const float*)d_in[6];
    const float* b_ih3 = (const float*)d_in[7];
    const float* b_hh3 = (const float*)d_in[8];
    float* out = (float*)d_out;

    lstm_fused_kernel<<<NBLK, 64, 0, stream>>>(
        input, W_ih1, W_hh1, b_ih1, b_hh1, W_ih3, W_hh3, b_ih3, b_hh3, out);
}

// Round 5
// 2282.312 us; speedup vs baseline: 2.1817x; 2.1817x over previous
//
#include <hip/hip_runtime.h>
#include <hip/hip_bf16.h>

#define SEQT 2000
#define NB   2048
#define H1   51
#define MROW 16
#define NBLK (NB / MROW)   // 128 blocks, 256 threads (4 waves)
#define PADK 168           // shorts per staged row (336 B, 16B-aligned, 8-bank spread)
#define OSTR 65            // Obuf row stride (floats) — odd, conflict-free

typedef float f32x4 __attribute__((ext_vector_type(4)));
typedef short s16x8 __attribute__((ext_vector_type(8)));
typedef unsigned u32x4 __attribute__((ext_vector_type(4)));
typedef unsigned u32x2 __attribute__((ext_vector_type(2)));

__device__ __forceinline__ short f2bf(float f) { __hip_bfloat16 b(f); return *(short*)&b; }
__device__ __forceinline__ float bf2f(short s) { __hip_bfloat16 b; *(short*)&b = s; return (float)b; }
__device__ __forceinline__ float rbf(float f) { return bf2f(f2bf(f)); }
__device__ __forceinline__ float fastrcp(float x) { return __builtin_amdgcn_rcpf(x); }
__device__ __forceinline__ float sigf(float x) { return fastrcp(1.f + __expf(-x)); }
__device__ __forceinline__ float tanhfast(float x) { return 1.f - 2.f * fastrcp(__expf(2.f * x) + 1.f); }

__device__ __forceinline__ unsigned rne_bf16(float v) {
    unsigned b = __float_as_uint(v);
    return (b + 0x7fffu + ((b >> 16) & 1u)) >> 16;
}

__device__ __forceinline__ f32x4 mfma16(s16x8 a, s16x8 b, f32x4 c) {
    return __builtin_amdgcn_mfma_f32_16x16x32_bf16(a, b, c, 0, 0, 0);
}

// ---------------------------------------------------------------------------
// Staged-vector column map, K=160 (5 k-tiles of 32). Columns permuted so each
// wave's epilogue writes are CONTIGUOUS (1 b128 + 1 b64 per 4-tile wave):
//   pairs  (h_hi,h_lo) x Whh_hi: col = (sl*4+kq)*8 + 2*i + (0|1), sl=0..2,
//          i=0..3 -> tile sl*4+i, u = 4*tile+kq.  w1 pairs: col 96+2*kq (tile12)
//   singles h_hi x Whh_lo:       col = 104 + (sl*4+kq)*4 + i.  w1: col 152+kq
//   cols 156..159: zero pad.
// x and bias are NOT in the MFMA anymore: gates = acc + fma(Wih_f32, x, bias)
// in the epilogue (f32-exact, frees the columns for the coalesced layout).
// MFMA A=weights(permuted to match), B=staged vector. C/D: lane (kq,iloc)
// holds gates of unit u = tile*4+kq for batch row m = iloc.
// LSTM3 (H3=1): each tile-wave folds z-partials over its own tiles (4 fma/tile)
// and writes one f32x4/lane; wave 1 tree-sums 16 scalars next step.
// ---------------------------------------------------------------------------

// A-operand value for gate-row n (valid_row = u_r < H1) at permuted column k.
__device__ __forceinline__ float aval(const float* __restrict__ W_hh1, int n,
                                      bool valid_row, int k) {
    if (!valid_row) return 0.f;
    int u; bool lo_w;
    if (k < 96) {
        const int gp = k >> 3, j = k & 7;
        const int sl = gp >> 2, kq2 = gp & 3;
        u = 4 * (sl * 4 + (j >> 1)) + kq2; lo_w = false;
    } else if (k < 104) {
        u = 48 + ((k - 96) >> 1); lo_w = false;
    } else if (k < 152) {
        const int d = k - 104;
        const int gp = d >> 2, j = d & 3;
        const int sl = gp >> 2, kq2 = gp & 3;
        u = 4 * (sl * 4 + j) + kq2; lo_w = true;
    } else if (k < 156) {
        u = 48 + (k - 152); lo_w = true;
    } else {
        return 0.f;
    }
    if (u >= H1) return 0.f;
    const float wv = W_hh1[n * H1 + u];
    return lo_w ? (wv - rbf(wv)) : rbf(wv);
}

template <int SL, int NTc>
__device__ __forceinline__ void run_tiles(
    const s16x8 (&Wfr)[4][5], const s16x8 (&hf)[5],
    const float (&Wih)[4][4], const float (&Bia)[4][4], const float (&W3c)[4][4],
    float (&c1st)[4], const float xm,
    short* __restrict__ Hw, float* __restrict__ Zw,
    const int iloc, const int kq) {
    f32x4 acc[4];
#pragma unroll
    for (int i = 0; i < NTc; ++i) {
        f32x4 a0 = (f32x4){0.f, 0.f, 0.f, 0.f};
        f32x4 a1 = (f32x4){0.f, 0.f, 0.f, 0.f};
        a0 = mfma16(Wfr[i][0], hf[0], a0);
        a1 = mfma16(Wfr[i][1], hf[1], a1);
        a0 = mfma16(Wfr[i][2], hf[2], a0);
        a1 = mfma16(Wfr[i][3], hf[3], a1);
        a0 = mfma16(Wfr[i][4], hf[4], a0);
        acc[i] = a0 + a1;
    }
    unsigned hp[4];
    float zp0 = 0.f, zp1 = 0.f, zp2 = 0.f, zp3 = 0.f;
#pragma unroll
    for (int i = 0; i < NTc; ++i) {
        const float gi = acc[i][0] + fmaf(Wih[i][0], xm, Bia[i][0]);
        const float gf = acc[i][1] + fmaf(Wih[i][1], xm, Bia[i][1]);
        const float gg = acc[i][2] + fmaf(Wih[i][2], xm, Bia[i][2]);
        const float go = acc[i][3] + fmaf(Wih[i][3], xm, Bia[i][3]);
        float c1 = c1st[i];
        c1 = sigf(gf) * c1 + sigf(gi) * tanhfast(gg);
        c1st[i] = c1;
        const float h1 = sigf(go) * tanhfast(c1);
        // RTZ hi + RNE lo (combined error ~2^-17, matches prior rounds)
        const unsigned uv = __float_as_uint(h1);
        const unsigned hh = uv >> 16;
        const float hif = __uint_as_float(uv & 0xffff0000u);
        const unsigned ll = rne_bf16(h1 - hif);
        hp[i] = hh | (ll << 16);
        zp0 = fmaf(W3c[i][0], c1, zp0);
        zp1 = fmaf(W3c[i][1], c1, zp1);
        zp2 = fmaf(W3c[i][2], c1, zp2);
        zp3 = fmaf(W3c[i][3], c1, zp3);
    }
    const int base = iloc * PADK;
    if (NTc == 4) {
        *(u32x4*)&Hw[base + (SL * 4 + kq) * 8] =
            (u32x4){hp[0], hp[1], hp[2], hp[3]};
        const unsigned s01 = (hp[0] & 0xffffu) | (hp[1] << 16);
        const unsigned s23 = (hp[2] & 0xffffu) | (hp[3] << 16);
        *(u32x2*)&Hw[base + 104 + (SL * 4 + kq) * 4] = (u32x2){s01, s23};
    } else {
        *(unsigned*)&Hw[base + 96 + kq * 2] = hp[0];
        Hw[base + 152 + kq] = (short)hp[0];
    }
    *(f32x4*)Zw = (f32x4){zp0, zp1, zp2, zp3};
}

// Fill one 64-step x-chunk (raw f32) into Xf.
__device__ __forceinline__ void xchunk_fill(const float* __restrict__ input, int r0, int c,
                                            int lane, float (*Xb)[64 * 16]) {
    const int m = lane & 15, q = lane >> 4;
    const int tt = c * 64 + q * 16;
    f32x4 v[4];
    if (tt < SEQT) {
        const float* src = input + (size_t)(r0 + m) * SEQT + tt;
#pragma unroll
        for (int p = 0; p < 4; ++p) v[p] = *(const f32x4*)(src + 4 * p);
    } else {
#pragma unroll
        for (int p = 0; p < 4; ++p) v[p] = (f32x4){0.f, 0.f, 0.f, 0.f};
    }
#pragma unroll
    for (int p = 0; p < 4; ++p)
#pragma unroll
        for (int j = 0; j < 4; ++j)
            Xb[c & 1][(q * 16 + p * 4 + j) * 16 + m] = v[p][j];
}

__global__ void __launch_bounds__(256)
__attribute__((amdgpu_waves_per_eu(1)))
lstm_fused_kernel(const float* __restrict__ input,
                  const float* __restrict__ W_ih1,
                  const float* __restrict__ W_hh1,
                  const float* __restrict__ b_ih1,
                  const float* __restrict__ b_hh1,
                  const float* __restrict__ W_ih3,
                  const float* __restrict__ W_hh3,
                  const float* __restrict__ b_ih3,
                  const float* __restrict__ b_hh3,
                  float* __restrict__ out) {
    const int t = threadIdx.x;
    const int w = t >> 6;          // wave 0..3
    const int lane = t & 63;
    const int iloc = lane & 15, kq = lane >> 4;
    const int r0 = blockIdx.x * MROW;

    __shared__ short Hst[2][MROW * PADK];      // staged h rows, parity dbuf
    __shared__ float Obuf[2][MROW * OSTR];     // c3 chunks
    __shared__ float Xf[2][64 * 16];           // raw f32 x, 64-step chunks
    __shared__ float Zbuf[2][4 * 4 * 16 * 4];  // z-partials [w][kq][m][g]
    __shared__ float Ztr[MROW * 4];            // LSTM3 gate-activation transpose

    // tile map: w0 {0-3} sl0, w2 {4-7} sl1, w3 {8-11} sl2, w1 {12} + LSTM3 + x
    const int NT = (w == 1) ? 1 : 4;
    const int tb = (w == 0) ? 0 : (w == 1) ? 12 : (w == 2) ? 4 : 8;

    // ---- A-operand weight fragments (permuted column map) ----
    s16x8 Wfr[4][5];
#pragma unroll
    for (int i = 0; i < 4; ++i) {
        if (i < NT) {
            const int np = (tb + i) * 16 + iloc;
            const int u_r = np >> 2, g_r = np & 3;
            const int n = g_r * H1 + u_r;
            const bool vr = (u_r < H1);
#pragma unroll
            for (int kt = 0; kt < 5; ++kt) {
                s16x8 bf;
#pragma unroll
                for (int j = 0; j < 8; ++j)
                    bf[j] = f2bf(aval(W_hh1, n, vr, kt * 32 + kq * 8 + j));
                Wfr[i][kt] = bf;
            }
        }
    }

    // ---- per-lane f32 epilogue constants: Wih, bias, W3 (unit u = tile*4+kq) ----
    float Wih[4][4], Bia[4][4], W3c[4][4];
#pragma unroll
    for (int i = 0; i < 4; ++i) {
        const int u = (tb + i) * 4 + kq;
        const bool ok = (i < NT) && (u < H1);
#pragma unroll
        for (int g = 0; g < 4; ++g) {
            Wih[i][g] = ok ? W_ih1[g * H1 + u] : 0.f;
            Bia[i][g] = ok ? (b_ih1[g * H1 + u] + b_hh1[g * H1 + u]) : 0.f;
            W3c[i][g] = ok ? W_ih3[g * H1 + u] : 0.f;
        }
    }

    // ---- LSTM3 per-lane activation constants: lane (m,g3) ----
    const int g3 = lane >> 4;
    const float whh3g = W_hh3[g3];
    const float b3g = b_ih3[g3] + b_hh3[g3];
    const float kg = (g3 == 2) ? 2.f : -1.f;
    const float ag = (g3 == 2) ? -2.f : 1.f;
    const float bg = (g3 == 2) ? 1.f : 0.f;

    // ---- LDS init ----
    for (int idx = t; idx < 2 * MROW * PADK; idx += 256)
        ((short*)Hst)[idx] = 0;   // h(0)=0; pad cols stay 0 forever
    if (w == 1) {                 // prefill x chunks 0 and 1
        xchunk_fill(input, r0, 0, lane, Xf);
        xchunk_fill(input, r0, 1, lane, Xf);
    }
    float c1st[4] = {0.f, 0.f, 0.f, 0.f};
    float h3 = 0.f, c3 = 0.f;   // LSTM3 state (wave 1, lanes 0..15 valid)
    float h3b = 0.f;            // h3 broadcast across wave-1 lanes (per m)

#pragma unroll 1
    for (int ts = 0; ts <= SEQT; ++ts) {
        __syncthreads();
        const int rb = (ts + 1) & 1, wb = ts & 1;

        // ---- reads first: LDS latency overlaps the rest of the step ----
        s16x8 hf[5];
        float xm = 0.f;
        if (ts < SEQT) {
#pragma unroll
            for (int kt = 0; kt < 5; ++kt)
                hf[kt] = *(const s16x8*)&Hst[rb][iloc * PADK + kt * 32 + kq * 8];
            xm = Xf[(ts >> 6) & 1][(ts & 63) * 16 + iloc];
        }
        float zv[16];
        if (w == 1 && ts >= 1) {
            const int m2 = lane & 15;
#pragma unroll
            for (int q = 0; q < 16; ++q)
                zv[q] = Zbuf[rb][(q * 16 + m2) * 4 + g3];
        }

        // ---- coalesced dump of finished 64-chunk ----
        if (ts >= 65 && (ts & 63) == 1) {
            const int c = (ts >> 6) - 1;
#pragma unroll
            for (int rep = 0; rep < 4; ++rep) {
                const int row = w + 4 * rep;
                out[(size_t)(r0 + row) * SEQT + c * 64 + lane] =
                    Obuf[c & 1][row * OSTR + lane];
            }
        }

        // ---- x chunk prefetch: issue loads early (store at step bottom) ----
        const bool fill = (w == 1) && (ts < SEQT) && ((ts & 63) == 0) &&
                          (ts >= 64) && ((ts >> 6) < 31);
        const int fc = (ts >> 6) + 1;
        f32x4 xv[4];
        if (fill) {
            const int fm = lane & 15, fq = lane >> 4;
            const int tt = fc * 64 + fq * 16;
            if (tt < SEQT) {
                const float* src = input + (size_t)(r0 + fm) * SEQT + tt;
#pragma unroll
                for (int p = 0; p < 4; ++p) xv[p] = *(const f32x4*)(src + 4 * p);
            } else {
#pragma unroll
                for (int p = 0; p < 4; ++p) xv[p] = (f32x4){0.f, 0.f, 0.f, 0.f};
            }
        }

        if (ts < SEQT) {
            short* Hw = &Hst[wb][0];
            float* Zw = &Zbuf[wb][((w * 4 + kq) * 16 + iloc) * 4];
            if (w == 0) {
                run_tiles<0, 4>(Wfr, hf, Wih, Bia, W3c, c1st, xm, Hw, Zw, iloc, kq);
            } else if (w == 2) {
                run_tiles<1, 4>(Wfr, hf, Wih, Bia, W3c, c1st, xm, Hw, Zw, iloc, kq);
            } else if (w == 3) {
                run_tiles<2, 4>(Wfr, hf, Wih, Bia, W3c, c1st, xm, Hw, Zw, iloc, kq);
            } else {
                run_tiles<3, 1>(Wfr, hf, Wih, Bia, W3c, c1st, xm, Hw, Zw, iloc, kq);
            }
        }

        // ---- LSTM3 for step ts-1 (wave 1): tree-sum z + 64-lane activations ----
        if (w == 1 && ts >= 1) {
            const float z =
                (((zv[0] + zv[1]) + (zv[2] + zv[3])) +
                 ((zv[4] + zv[5]) + (zv[6] + zv[7]))) +
                (((zv[8] + zv[9]) + (zv[10] + zv[11])) +
                 ((zv[12] + zv[13]) + (zv[14] + zv[15])));
            const float pre = z + fmaf(whh3g, h3b, b3g);
            const float act = bg + ag * fastrcp(__expf(kg * pre) + 1.f);
            Ztr[(lane & 15) * 4 + g3] = act;
            __builtin_amdgcn_wave_barrier();   // keep write before read (1 wave)
            const int s = ts - 1;
            if (lane < MROW) {
                const f32x4 a4 = *(const f32x4*)&Ztr[lane * 4];   // i,f,g,o
                c3 = a4[1] * c3 + a4[0] * a4[2];
                h3 = a4[3] * tanhfast(c3);
                Obuf[(s >> 6) & 1][lane * OSTR + (s & 63)] = c3;
            }
            h3b = __shfl(h3, lane & 15, 64);
        }

        // ---- x chunk prefetch: store (loads had the step to land) ----
        if (fill) {
            const int fm = lane & 15, fq = lane >> 4;
#pragma unroll
            for (int p = 0; p < 4; ++p)
#pragma unroll
                for (int j = 0; j < 4; ++j)
                    Xf[fc & 1][(fq * 16 + p * 4 + j) * 16 + fm] = xv[p][j];
        }
    }

    __syncthreads();
    // tail: steps 1984..1999 (chunk 31, parity 1, 16 cols)
    {
        const int row = t >> 4, pos = t & 15;
        out[(size_t)(r0 + row) * SEQT + 1984 + pos] = Obuf[1][row * OSTR + pos];
    }
}

extern "C" void kernel_launch(void* const* d_in, const int* in_sizes, int n_in,
                              void* d_out, int out_size, void* d_ws, size_t ws_size,
                              hipStream_t stream) {
    const float* input = (const float*)d_in[0];
    const float* W_ih1 = (const float*)d_in[1];
    const float* W_hh1 = (const float*)d_in[2];
    const float* b_ih1 = (const float*)d_in[3];
    const float* b_hh1 = (const float*)d_in[4];
    const float* W_ih3 = (const float*)d_in[5];
    const float* W_hh3 = (const float*)d_in[6];
    const float* b_ih3 = (const float*)d_in[7];
    const float* b_hh3 = (const float*)d_in[8];
    float* out = (float*)d_out;

    lstm_fused_kernel<<<NBLK, 256, 0, stream>>>(
        input, W_ih1, W_hh1, b_ih1, b_hh1, W_ih3, W_hh3, b_ih3, b_hh3, out);
}

// Round 6
// 1905.383 us; speedup vs baseline: 2.6133x; 1.1978x over previous
//
#include <hip/hip_runtime.h>
#include <hip/hip_bf16.h>

#define SEQT 2000
#define NB   2048
#define H1   51
#define MROW 16
#define NBLK (NB / MROW)   // 128 blocks, 256 threads (4 waves)
#define PADK 168           // shorts per staged row (336 B = 21*16, 16B-aligned)
#define OSTR 65            // Obuf row stride (floats) — odd, conflict-free

typedef float f32x4 __attribute__((ext_vector_type(4)));
typedef short s16x8 __attribute__((ext_vector_type(8)));
typedef unsigned u32x4 __attribute__((ext_vector_type(4)));
typedef unsigned u32x2 __attribute__((ext_vector_type(2)));

__device__ __forceinline__ short f2bf(float f) { __hip_bfloat16 b(f); return *(short*)&b; }
__device__ __forceinline__ float bf2f(short s) { __hip_bfloat16 b; *(short*)&b = s; return (float)b; }
__device__ __forceinline__ float rbf(float f) { return bf2f(f2bf(f)); }
__device__ __forceinline__ float fastrcp(float x) { return __builtin_amdgcn_rcpf(x); }
__device__ __forceinline__ float tanhfast(float x) { return 1.f - 2.f * fastrcp(__expf(2.f * x) + 1.f); }

__device__ __forceinline__ unsigned rne_bf16(float v) {
    unsigned b = __float_as_uint(v);
    return (b + 0x7fffu + ((b >> 16) & 1u)) >> 16;
}
// packed (hi | lo<<16), both RNE — off the hot path (x staging)
__device__ __forceinline__ unsigned pack_hilo(float v) {
    const unsigned hh = rne_bf16(v);
    const float hi = __uint_as_float(hh << 16);
    const unsigned hl = rne_bf16(v - hi);
    return hh | (hl << 16);
}

__device__ __forceinline__ f32x4 mfma16(s16x8 a, s16x8 b, f32x4 c) {
    return __builtin_amdgcn_mfma_f32_16x16x32_bf16(a, b, c, 0, 0, 0);
}

// ---------------------------------------------------------------------------
// Staged-vector column map, K=160 (5 k-tiles of 32). Columns permuted so every
// per-step write is coalesced, while keeping r2's EXACT MFMA semantics
// (x and bias stay inside the matmul):
//   0..95   : (h_hi,h_lo) pairs vs Whh_hi. col=(sl*4+kq)*8+2i+{0,1}, tile=sl*4+i
//   96..101 : w1 pairs (u=48+kq, kq=0..2) vs Whh_hi
//   102,103 : x_hi, x_lo vs Wih_hi
//   104..151: h_hi singles vs Whh_lo. col=104+(sl*4+kq)*4+i
//   152..154: w1 singles (u=48+kq) vs Whh_lo
//   155     : x_hi vs Wih_lo
//   156,157 : 1.0 vs bias_hi / bias_lo    158,159: 0    160..167: scratch
// Gate rows n' = u*4+g (13 N-tiles). MFMA A=weights, B=staged vector.
// C/D: lane (kq,iloc) holds all 4 gates of unit u = tile*4+kq, batch row iloc.
// Tile-wave epilogue: merged-rcp activations (7 trans/tile), single b128 pair-
// write + single b64 single-write + single b128 C1 store (permuted u-order).
// LSTM3 (H3=1): w1 reads C1 rows, 52-FMA dot with permuted Wz, 64-lane
// activation spread, Ztr transpose, c3/h3 on lanes 0..15 (r2-identical).
// ---------------------------------------------------------------------------

__device__ __forceinline__ float aval(const float* __restrict__ W_hh1,
                                      const float* __restrict__ W_ih1,
                                      const float* __restrict__ b_ih1,
                                      const float* __restrict__ b_hh1,
                                      int n, bool vr, int k) {
    if (!vr) return 0.f;
    if (k < 96) {
        const int gp = k >> 3, j = k & 7;
        const int u = 4 * ((gp >> 2) * 4 + (j >> 1)) + (gp & 3);
        return rbf(W_hh1[n * H1 + u]);
    } else if (k < 102) {
        const int u = 48 + ((k - 96) >> 1);
        return rbf(W_hh1[n * H1 + u]);
    } else if (k < 104) {
        return rbf(W_ih1[n]);                    // x_hi / x_lo vs Wih_hi
    } else if (k < 152) {
        const int d = k - 104;
        const int gp = d >> 2;
        const int u = 4 * ((gp >> 2) * 4 + (d & 3)) + (gp & 3);
        const float wv = W_hh1[n * H1 + u];
        return wv - rbf(wv);
    } else if (k < 155) {
        const int u = 48 + (k - 152);
        const float wv = W_hh1[n * H1 + u];
        return wv - rbf(wv);
    } else if (k == 155) {
        const float wv = W_ih1[n];
        return wv - rbf(wv);
    } else if (k == 156) {
        return rbf(b_ih1[n] + b_hh1[n]);
    } else if (k == 157) {
        const float bv = b_ih1[n] + b_hh1[n];
        return bv - rbf(bv);
    }
    return 0.f;
}

template <int SL, int NTc>
__device__ __forceinline__ void run_tiles(const s16x8 (&Wfr)[4][5], const s16x8 (&hf)[5],
                                          float (&c1st)[4], short* __restrict__ Hw,
                                          float* __restrict__ C1w,
                                          const int iloc, const int kq) {
    f32x4 acc[4];
#pragma unroll
    for (int i = 0; i < NTc; ++i) {
        f32x4 a = (f32x4){0.f, 0.f, 0.f, 0.f};
        a = mfma16(Wfr[i][0], hf[0], a);
        a = mfma16(Wfr[i][1], hf[1], a);
        a = mfma16(Wfr[i][2], hf[2], a);
        a = mfma16(Wfr[i][3], hf[3], a);
        a = mfma16(Wfr[i][4], hf[4], a);
        acc[i] = a;
    }
    unsigned hp[4];
    float cl[4];
#pragma unroll
    for (int i = 0; i < NTc; ++i) {
        const float gi = acc[i][0], gf = acc[i][1], gg = acc[i][2], go = acc[i][3];
        // merged-rcp LSTM cell: one rcp for {sig(gf), sig(gi), tanh(gg)}
        const float ef = __expf(-gf);
        const float ei = __expf(-gi);
        const float tg = __expf(-gg);
        const float eg = tg * tg;                 // e^(-2gg)
        const float pf = 1.f + ef, pi_ = 1.f + ei, pg = 1.f + eg, mg = 1.f - eg;
        const float pp = pi_ * pg;
        float c1 = c1st[i];
        c1 = fmaf(c1, pp, pf * mg) * fastrcp(pf * pp);
        c1st[i] = c1;
        cl[i] = c1;
        // h1 = sig(go)*tanh(c1), one rcp (clamp exp arg: c1 very negative)
        const float eo = __expf(-go);
        const float ec = __expf(fminf(80.f, -2.f * c1));
        const float h1 = (1.f - ec) * fastrcp((1.f + eo) * (1.f + ec));
        // RTZ hi + RNE lo pack (combined error ~2^-17)
        const unsigned uv = __float_as_uint(h1);
        const unsigned hh = uv >> 16;
        const float hif = __uint_as_float(uv & 0xffff0000u);
        const unsigned ll = rne_bf16(h1 - hif);
        hp[i] = hh | (ll << 16);
    }
    const int base = iloc * PADK;
    if (NTc == 4) {
        *(u32x4*)&Hw[base + (SL * 4 + kq) * 8] =
            (u32x4){hp[0], hp[1], hp[2], hp[3]};
        const unsigned s01 = (hp[0] & 0xffffu) | (hp[1] << 16);
        const unsigned s23 = (hp[2] & 0xffffu) | (hp[3] << 16);
        *(u32x2*)&Hw[base + 104 + (SL * 4 + kq) * 4] = (u32x2){s01, s23};
        *(f32x4*)&C1w[iloc * 52 + SL * 16 + kq * 4] =
            (f32x4){cl[0], cl[1], cl[2], cl[3]};
    } else {
        const bool ok = (48 + kq) < H1;           // kq==3 -> scratch
        *(unsigned*)&Hw[base + (ok ? 96 + 2 * kq : 160)] = hp[0];
        Hw[base + (ok ? 152 + kq : 164)] = (short)hp[0];
        C1w[iloc * 52 + 48 + kq] = cl[0];         // p=51 is scratch (Wz[51]=0)
    }
}

// Fill one 64-step x-chunk into Xbuf (wave 1, all 64 lanes), packed hi|lo.
__device__ __forceinline__ void xchunk_fill(const float* __restrict__ input, int r0, int c,
                                            int lane, unsigned (*Xb)[64 * 16]) {
    const int m = lane & 15, q = lane >> 4;
    const int tt = c * 64 + q * 16;
    f32x4 v[4];
    if (tt < SEQT) {
        const float* src = input + (size_t)(r0 + m) * SEQT + tt;
#pragma unroll
        for (int p = 0; p < 4; ++p) v[p] = *(const f32x4*)(src + 4 * p);
    } else {
#pragma unroll
        for (int p = 0; p < 4; ++p) v[p] = (f32x4){0.f, 0.f, 0.f, 0.f};
    }
#pragma unroll
    for (int p = 0; p < 4; ++p)
#pragma unroll
        for (int j = 0; j < 4; ++j)
            Xb[c & 1][(q * 16 + p * 4 + j) * 16 + m] = pack_hilo(v[p][j]);
}

__global__ void __launch_bounds__(256)
__attribute__((amdgpu_waves_per_eu(1)))
lstm_fused_kernel(const float* __restrict__ input,
                  const float* __restrict__ W_ih1,
                  const float* __restrict__ W_hh1,
                  const float* __restrict__ b_ih1,
                  const float* __restrict__ b_hh1,
                  const float* __restrict__ W_ih3,
                  const float* __restrict__ W_hh3,
                  const float* __restrict__ b_ih3,
                  const float* __restrict__ b_hh3,
                  float* __restrict__ out) {
    const int t = threadIdx.x;
    const int w = t >> 6;          // wave 0..3
    const int lane = t & 63;
    const int iloc = lane & 15, kq = lane >> 4;
    const int r0 = blockIdx.x * MROW;

    __shared__ short Hst[2][MROW * PADK];      // staged h/x/bias rows, parity dbuf
    __shared__ float C1buf[2][MROW * 52];      // raw f32 c1 (permuted u), parity dbuf
    __shared__ float Obuf[2][MROW * OSTR];     // c3 chunks
    __shared__ unsigned Xbuf[2][64 * 16];      // packed x hi/lo, 64-step chunks
    __shared__ float Ztr[MROW * 4];            // LSTM3 gate-activation transpose

    // tile assignment: w0 {0-3} SL0, w2 {4-7} SL1, w3 {8-11} SL2, w1 {12}+LSTM3+x
    const int NT = (w == 1) ? 1 : 4;
    const int tb = (w == 0) ? 0 : (w == 1) ? 12 : (w == 2) ? 4 : 8;

    // ---- gate-row weight fragments (A-operand, permuted map) ----
    s16x8 Wfr[4][5];
#pragma unroll
    for (int i = 0; i < 4; ++i) {
        if (i < NT) {
            const int np = (tb + i) * 16 + iloc;
            const int u_r = np >> 2, g_r = np & 3;
            const int n = g_r * H1 + u_r;
            const bool vr = (u_r < H1);
#pragma unroll
            for (int kt = 0; kt < 5; ++kt) {
                s16x8 bf;
#pragma unroll
                for (int j = 0; j < 8; ++j)
                    bf[j] = f2bf(aval(W_hh1, W_ih1, b_ih1, b_hh1, n, vr,
                                      kt * 32 + kq * 8 + j));
                Wfr[i][kt] = bf;
            }
        }
    }

    // ---- wave 1: LSTM3 constants. lane (m,g3): m = lane&15, g3 = lane>>4 ----
    const int g3 = lane >> 4;
    float Wz[52];
    if (w == 1) {
#pragma unroll
        for (int p = 0; p < 52; ++p) {
            const int u = (p < 48) ? (16 * (p >> 4) + 4 * (p & 3) + ((p >> 2) & 3))
                                   : p;
            Wz[p] = (u < H1) ? W_ih3[g3 * H1 + u] : 0.f;
        }
    }
    const float whh3g = W_hh3[g3];
    const float b3g = b_ih3[g3] + b_hh3[g3];
    // activation form: act = bg + ag * rcp(exp(kg*x)+1)
    const float kg = (g3 == 2) ? 2.f : -1.f;
    const float ag = (g3 == 2) ? -2.f : 1.f;
    const float bg = (g3 == 2) ? 1.f : 0.f;

    // ---- LDS init ----
    for (int idx = t; idx < 2 * MROW * PADK; idx += 256)
        ((short*)Hst)[idx] = 0;
    for (int idx = t; idx < 2 * MROW * 52; idx += 256)
        ((float*)C1buf)[idx] = 0.f;
    __syncthreads();   // zeros before targeted writes
    if (t < MROW) {
        const int m = t;
#pragma unroll
        for (int p = 0; p < 2; ++p) {
            Hst[p][m * PADK + 156] = (short)0x3F80;   // 1.0 (bias cols)
            Hst[p][m * PADK + 157] = (short)0x3F80;
        }
        const float x0 = input[(size_t)(r0 + m) * SEQT];
        const unsigned xp = pack_hilo(x0);
        Hst[1][m * PADK + 102] = (short)xp;   // window 0 reads parity 1
        Hst[1][m * PADK + 103] = (short)(xp >> 16);
        Hst[1][m * PADK + 155] = (short)xp;
    }
    if (w == 1) {                 // prefill x chunks 0 and 1
        xchunk_fill(input, r0, 0, lane, Xbuf);
        xchunk_fill(input, r0, 1, lane, Xbuf);
    }
    float c1st[4] = {0.f, 0.f, 0.f, 0.f};
    float h3 = 0.f, c3 = 0.f;   // LSTM3 state (wave 1, lanes 0..15 valid)
    float h3b = 0.f;            // h3 broadcast across wave-1 lanes (per m)

#pragma unroll 1
    for (int ts = 0; ts <= SEQT; ++ts) {
        __syncthreads();
        const int rb = (ts + 1) & 1, wb = ts & 1;

        // ---- reads first: LDS latency overlaps the rest of the step ----
        s16x8 hf[5];
        if (ts < SEQT) {
#pragma unroll
            for (int kt = 0; kt < 5; ++kt)
                hf[kt] = *(const s16x8*)&Hst[rb][iloc * PADK + kt * 32 + kq * 8];
        }
        f32x4 c1v[13];
        if (w == 1 && ts >= 1) {
            const float* cr = &C1buf[rb][(lane & 15) * 52];
#pragma unroll
            for (int j = 0; j < 13; ++j)
                c1v[j] = *(const f32x4*)(cr + 4 * j);
        }

        // ---- coalesced dump of finished 64-chunk ----
        if (ts >= 65 && (ts & 63) == 1) {
            const int c = (ts >> 6) - 1;
#pragma unroll
            for (int rep = 0; rep < 4; ++rep) {
                const int row = w + 4 * rep;
                out[(size_t)(r0 + row) * SEQT + c * 64 + lane] =
                    Obuf[c & 1][row * OSTR + lane];
            }
        }

        // ---- x chunk prefetch: issue loads early (store at step bottom) ----
        const bool fill = (w == 1) && (ts < SEQT) && ((ts & 63) == 0) &&
                          (ts >= 64) && ((ts >> 6) < 31);
        const int fc = (ts >> 6) + 1;
        f32x4 xv[4];
        if (fill) {
            const int fm = lane & 15, fq = lane >> 4;
            const int tt = fc * 64 + fq * 16;
            if (tt < SEQT) {
                const float* src = input + (size_t)(r0 + fm) * SEQT + tt;
#pragma unroll
                for (int p = 0; p < 4; ++p) xv[p] = *(const f32x4*)(src + 4 * p);
            } else {
#pragma unroll
                for (int p = 0; p < 4; ++p) xv[p] = (f32x4){0.f, 0.f, 0.f, 0.f};
            }
        }

        if (ts < SEQT) {
            short* Hw = &Hst[wb][0];
            float* C1w = &C1buf[wb][0];
            if (w == 0) {
                run_tiles<0, 4>(Wfr, hf, c1st, Hw, C1w, iloc, kq);
            } else if (w == 2) {
                run_tiles<1, 4>(Wfr, hf, c1st, Hw, C1w, iloc, kq);
            } else if (w == 3) {
                run_tiles<2, 4>(Wfr, hf, c1st, Hw, C1w, iloc, kq);
            } else {
                // w1: x staging for step ts+1 (cols 102/103/155)
                const int t1 = ts + 1;
                if (t1 < SEQT) {
                    const int m2 = lane & 15;
                    const unsigned pv = Xbuf[(t1 >> 6) & 1][(t1 & 63) * 16 + m2];
                    *(unsigned*)&Hw[m2 * PADK + 102] = pv;
                    Hw[m2 * PADK + 155] = (short)pv;
                }
                run_tiles<3, 1>(Wfr, hf, c1st, Hw, C1w, iloc, kq);
            }
        }

        // ---- LSTM3 for step ts-1 (wave 1): dot + 64-lane activations ----
        if (w == 1 && ts >= 1) {
            float d0 = 0.f, d1 = 0.f, d2 = 0.f, d3 = 0.f;
#pragma unroll
            for (int j = 0; j < 13; ++j) {
                d0 = fmaf(Wz[4 * j + 0], c1v[j][0], d0);
                d1 = fmaf(Wz[4 * j + 1], c1v[j][1], d1);
                d2 = fmaf(Wz[4 * j + 2], c1v[j][2], d2);
                d3 = fmaf(Wz[4 * j + 3], c1v[j][3], d3);
            }
            const float z = (d0 + d1) + (d2 + d3);
            const float pre = z + fmaf(whh3g, h3b, b3g);
            const float act = bg + ag * fastrcp(__expf(kg * pre) + 1.f);
            Ztr[(lane & 15) * 4 + g3] = act;
            __builtin_amdgcn_wave_barrier();   // keep write before read (1 wave)
            const int s = ts - 1;
            if (lane < MROW) {
                const f32x4 a4 = *(const f32x4*)&Ztr[lane * 4];   // i,f,g,o
                c3 = a4[1] * c3 + a4[0] * a4[2];
                h3 = a4[3] * tanhfast(c3);
                Obuf[(s >> 6) & 1][lane * OSTR + (s & 63)] = c3;
            }
            h3b = __shfl(h3, lane & 15, 64);
        }

        // ---- x chunk prefetch: pack + store (loads had the step to land) ----
        if (fill) {
            const int fm = lane & 15, fq = lane >> 4;
#pragma unroll
            for (int p = 0; p < 4; ++p)
#pragma unroll
                for (int j = 0; j < 4; ++j)
                    Xbuf[fc & 1][(fq * 16 + p * 4 + j) * 16 + fm] =
                        pack_hilo(xv[p][j]);
        }
    }

    __syncthreads();
    // tail: steps 1984..1999 (chunk 31, parity 1)
    {
        const int row = t >> 4, pos = t & 15;
        out[(size_t)(r0 + row) * SEQT + 1984 + pos] = Obuf[1][row * OSTR + pos];
    }
}

extern "C" void kernel_launch(void* const* d_in, const int* in_sizes, int n_in,
                              void* d_out, int out_size, void* d_ws, size_t ws_size,
                              hipStream_t stream) {
    const float* input = (const float*)d_in[0];
    const float* W_ih1 = (const float*)d_in[1];
    const float* W_hh1 = (const float*)d_in[2];
    const float* b_ih1 = (const float*)d_in[3];
    const float* b_hh1 = (const float*)d_in[4];
    const float* W_ih3 = (const float*)d_in[5];
    const float* W_hh3 = (const float*)d_in[6];
    const float* b_ih3 = (const float*)d_in[7];
    const float* b_hh3 = (const float*)d_in[8];
    float* out = (float*)d_out;

    lstm_fused_kernel<<<NBLK, 256, 0, stream>>>(
        input, W_ih1, W_hh1, b_ih1, b_hh1, W_ih3, W_hh3, b_ih3, b_hh3, out);
}

// Round 7
// 1903.248 us; speedup vs baseline: 2.6162x; 1.0011x over previous
//
#include <hip/hip_runtime.h>
#include <hip/hip_bf16.h>

#define SEQT 2000
#define NB   2048
#define H1   51
#define MROW 16
#define NBLK (NB / MROW)   // 128 blocks, 256 threads (4 waves)
#define PADK 168           // shorts per staged row (336 B = 21*16, 16B-aligned)
#define OSTR 65            // Obuf row stride (floats) — odd, conflict-free

// log2(e) and 2*log2(e)
#define L2E  1.4426950408889634f
#define L2E2 2.8853900817779268f

typedef float f32x4 __attribute__((ext_vector_type(4)));
typedef short s16x8 __attribute__((ext_vector_type(8)));
typedef unsigned u32x4 __attribute__((ext_vector_type(4)));
typedef unsigned u32x2 __attribute__((ext_vector_type(2)));

#if __has_builtin(__builtin_amdgcn_exp2f)
#define EXP2F(x) __builtin_amdgcn_exp2f(x)
#else
#define EXP2F(x) __expf((x) * 0.6931471805599453f)   // exp(x*ln2) == 2^x
#endif

__device__ __forceinline__ short f2bf(float f) { __hip_bfloat16 b(f); return *(short*)&b; }
__device__ __forceinline__ float bf2f(short s) { __hip_bfloat16 b; *(short*)&b = s; return (float)b; }
__device__ __forceinline__ float rbf(float f) { return bf2f(f2bf(f)); }
__device__ __forceinline__ float fastrcp(float x) { return __builtin_amdgcn_rcpf(x); }
__device__ __forceinline__ float tanhfast(float x) {
    return 1.f - 2.f * fastrcp(EXP2F(x * L2E2) + 1.f);
}

__device__ __forceinline__ unsigned rne_bf16(float v) {
    unsigned b = __float_as_uint(v);
    return (b + 0x7fffu + ((b >> 16) & 1u)) >> 16;
}
// packed (hi | lo<<16), both RNE — off the hot path (x staging)
__device__ __forceinline__ unsigned pack_hilo(float v) {
    const unsigned hh = rne_bf16(v);
    const float hi = __uint_as_float(hh << 16);
    const unsigned hl = rne_bf16(v - hi);
    return hh | (hl << 16);
}

__device__ __forceinline__ f32x4 mfma16(s16x8 a, s16x8 b, f32x4 c) {
    return __builtin_amdgcn_mfma_f32_16x16x32_bf16(a, b, c, 0, 0, 0);
}

// ---------------------------------------------------------------------------
// Staged-vector column map, K=160 (5 k-tiles of 32). Columns permuted so every
// per-step write is coalesced; x and bias live inside the matmul.
//   0..95   : (h_hi,h_lo) pairs vs Whh_hi. col=(sl*4+kq)*8+2i+{0,1}, tile=sl*4+i
//   96..101 : w1 pairs (u=48+kq, kq=0..2) vs Whh_hi
//   102,103 : x_hi, x_lo vs Wih_hi
//   104..151: h_hi singles vs Whh_lo. col=104+(sl*4+kq)*4+i
//   152..154: w1 singles (u=48+kq) vs Whh_lo
//   155     : x_hi vs Wih_lo
//   156,157 : 1.0 vs bias_hi / bias_lo    158,159: 0    160..167: scratch
// EXP2 FOLD: every A-row (gate row n' = u*4+g) is pre-scaled by
//   sc(g) = -log2e (g in {i,f,o}) or -2*log2e (g == tanh gate 2),
// so the MFMA accumulator directly yields the v_exp_f32 (2^x) argument:
//   e_gate = exp2(acc). No per-exp mul, no eg square.
// C/D: lane (kq,iloc) holds all 4 gates of unit u = tile*4+kq, batch row iloc.
// LSTM3 (H3=1): w1 reads C1 rows, 52-FMA dot with permuted+scaled Wz, 64-lane
// activation spread, Ztr transpose, c3/h3 on lanes 0..15.
// ---------------------------------------------------------------------------

__device__ __forceinline__ float aval(const float* __restrict__ W_hh1,
                                      const float* __restrict__ W_ih1,
                                      const float* __restrict__ b_ih1,
                                      const float* __restrict__ b_hh1,
                                      int n, float sc, bool vr, int k) {
    if (!vr) return 0.f;
    if (k < 96) {
        const int gp = k >> 3, j = k & 7;
        const int u = 4 * ((gp >> 2) * 4 + (j >> 1)) + (gp & 3);
        return rbf(sc * W_hh1[n * H1 + u]);
    } else if (k < 102) {
        const int u = 48 + ((k - 96) >> 1);
        return rbf(sc * W_hh1[n * H1 + u]);
    } else if (k < 104) {
        return rbf(sc * W_ih1[n]);               // x_hi / x_lo vs Wih_hi
    } else if (k < 152) {
        const int d = k - 104;
        const int gp = d >> 2;
        const int u = 4 * ((gp >> 2) * 4 + (d & 3)) + (gp & 3);
        const float wv = sc * W_hh1[n * H1 + u];
        return wv - rbf(wv);
    } else if (k < 155) {
        const int u = 48 + (k - 152);
        const float wv = sc * W_hh1[n * H1 + u];
        return wv - rbf(wv);
    } else if (k == 155) {
        const float wv = sc * W_ih1[n];
        return wv - rbf(wv);
    } else if (k == 156) {
        return rbf(sc * (b_ih1[n] + b_hh1[n]));
    } else if (k == 157) {
        const float bv = sc * (b_ih1[n] + b_hh1[n]);
        return bv - rbf(bv);
    }
    return 0.f;
}

template <int SL, int NTc>
__device__ __forceinline__ void run_tiles(const s16x8 (&Wfr)[4][5], const s16x8 (&hf)[5],
                                          float (&c1st)[4], short* __restrict__ Hw,
                                          float* __restrict__ C1w,
                                          const int iloc, const int kq) {
    f32x4 acc[4];
#pragma unroll
    for (int i = 0; i < NTc; ++i) {
        f32x4 a = (f32x4){0.f, 0.f, 0.f, 0.f};
        a = mfma16(Wfr[i][0], hf[0], a);
        a = mfma16(Wfr[i][1], hf[1], a);
        a = mfma16(Wfr[i][2], hf[2], a);
        a = mfma16(Wfr[i][3], hf[3], a);
        a = mfma16(Wfr[i][4], hf[4], a);
        acc[i] = a;
    }
    unsigned hp[4];
    float cl[4];
#pragma unroll
    for (int i = 0; i < NTc; ++i) {
        // acc already holds the exp2 arguments (weights pre-scaled by -log2e /
        // -2log2e), so transcendentals issue straight off the MFMA result.
        const float ei = EXP2F(acc[i][0]);        // e^{-gi}
        const float ef = EXP2F(acc[i][1]);        // e^{-gf}
        const float eg = EXP2F(acc[i][2]);        // e^{-2gg}
        const float eo = EXP2F(acc[i][3]);        // e^{-go}
        const float pf = 1.f + ef, pi_ = 1.f + ei, pg = 1.f + eg, mg = 1.f - eg;
        const float pp = pi_ * pg;
        float c1 = c1st[i];
        c1 = fmaf(c1, pp, pf * mg) * fastrcp(pf * pp);
        c1st[i] = c1;
        cl[i] = c1;
        // h1 = sig(go)*tanh(c1); clamp matches old exp-domain 80 (115.4/log2e)
        const float ec = EXP2F(fminf(115.4f, c1 * -L2E2));
        const float h1 = (1.f - ec) * fastrcp((1.f + eo) * (1.f + ec));
        // RNE hi + RNE lo via HW bf16 converts
        const __hip_bfloat16 bh(h1);
        const float df = h1 - (float)bh;
        const __hip_bfloat16 bl(df);
        hp[i] = (unsigned)*(const unsigned short*)&bh |
                ((unsigned)*(const unsigned short*)&bl << 16);
    }
    const int base = iloc * PADK;
    if (NTc == 4) {
        *(u32x4*)&Hw[base + (SL * 4 + kq) * 8] =
            (u32x4){hp[0], hp[1], hp[2], hp[3]};
        const unsigned s01 = (hp[0] & 0xffffu) | (hp[1] << 16);
        const unsigned s23 = (hp[2] & 0xffffu) | (hp[3] << 16);
        *(u32x2*)&Hw[base + 104 + (SL * 4 + kq) * 4] = (u32x2){s01, s23};
        *(f32x4*)&C1w[iloc * 52 + SL * 16 + kq * 4] =
            (f32x4){cl[0], cl[1], cl[2], cl[3]};
    } else {
        const bool ok = (48 + kq) < H1;           // kq==3 -> scratch
        *(unsigned*)&Hw[base + (ok ? 96 + 2 * kq : 160)] = hp[0];
        Hw[base + (ok ? 152 + kq : 164)] = (short)hp[0];
        C1w[iloc * 52 + 48 + kq] = cl[0];         // p=51 is scratch (Wz[51]=0)
    }
}

// Fill one 64-step x-chunk into Xbuf (wave 1, all 64 lanes), packed hi|lo.
__device__ __forceinline__ void xchunk_fill(const float* __restrict__ input, int r0, int c,
                                            int lane, unsigned (*Xb)[64 * 16]) {
    const int m = lane & 15, q = lane >> 4;
    const int tt = c * 64 + q * 16;
    f32x4 v[4];
    if (tt < SEQT) {
        const float* src = input + (size_t)(r0 + m) * SEQT + tt;
#pragma unroll
        for (int p = 0; p < 4; ++p) v[p] = *(const f32x4*)(src + 4 * p);
    } else {
#pragma unroll
        for (int p = 0; p < 4; ++p) v[p] = (f32x4){0.f, 0.f, 0.f, 0.f};
    }
#pragma unroll
    for (int p = 0; p < 4; ++p)
#pragma unroll
        for (int j = 0; j < 4; ++j)
            Xb[c & 1][(q * 16 + p * 4 + j) * 16 + m] = pack_hilo(v[p][j]);
}

__global__ void __launch_bounds__(256)
__attribute__((amdgpu_waves_per_eu(1)))
lstm_fused_kernel(const float* __restrict__ input,
                  const float* __restrict__ W_ih1,
                  const float* __restrict__ W_hh1,
                  const float* __restrict__ b_ih1,
                  const float* __restrict__ b_hh1,
                  const float* __restrict__ W_ih3,
                  const float* __restrict__ W_hh3,
                  const float* __restrict__ b_ih3,
                  const float* __restrict__ b_hh3,
                  float* __restrict__ out) {
    const int t = threadIdx.x;
    const int w = t >> 6;          // wave 0..3
    const int lane = t & 63;
    const int iloc = lane & 15, kq = lane >> 4;
    const int r0 = blockIdx.x * MROW;

    __shared__ short Hst[2][MROW * PADK];      // staged h/x/bias rows, parity dbuf
    __shared__ float C1buf[2][MROW * 52];      // raw f32 c1 (permuted u), parity dbuf
    __shared__ float Obuf[2][MROW * OSTR];     // c3 chunks
    __shared__ unsigned Xbuf[2][64 * 16];      // packed x hi/lo, 64-step chunks
    __shared__ float Ztr[MROW * 4];            // LSTM3 gate-activation transpose

    // tile assignment: w0 {0-3} SL0, w2 {4-7} SL1, w3 {8-11} SL2, w1 {12}+LSTM3+x
    const int NT = (w == 1) ? 1 : 4;
    const int tb = (w == 0) ? 0 : (w == 1) ? 12 : (w == 2) ? 4 : 8;

    // ---- gate-row weight fragments (A-operand, permuted map, exp2-scaled) ----
    s16x8 Wfr[4][5];
#pragma unroll
    for (int i = 0; i < 4; ++i) {
        if (i < NT) {
            const int np = (tb + i) * 16 + iloc;
            const int u_r = np >> 2, g_r = np & 3;
            const int n = g_r * H1 + u_r;
            const bool vr = (u_r < H1);
            const float sc = (g_r == 2) ? -L2E2 : -L2E;
#pragma unroll
            for (int kt = 0; kt < 5; ++kt) {
                s16x8 bf;
#pragma unroll
                for (int j = 0; j < 8; ++j)
                    bf[j] = f2bf(aval(W_hh1, W_ih1, b_ih1, b_hh1, n, sc, vr,
                                      kt * 32 + kq * 8 + j));
                Wfr[i][kt] = bf;
            }
        }
    }

    // ---- wave 1: LSTM3 constants (log2-scaled). lane (m,g3) ----
    const int g3 = lane >> 4;
    const float scg3 = (g3 == 2) ? L2E2 : -L2E;   // kg * log2e
    float Wz[52];
    if (w == 1) {
#pragma unroll
        for (int p = 0; p < 52; ++p) {
            const int u = (p < 48) ? (16 * (p >> 4) + 4 * (p & 3) + ((p >> 2) & 3))
                                   : p;
            Wz[p] = (u < H1) ? scg3 * W_ih3[g3 * H1 + u] : 0.f;
        }
    }
    const float whh3g = scg3 * W_hh3[g3];
    const float b3g = scg3 * (b_ih3[g3] + b_hh3[g3]);
    // activation form: act = bg + ag * rcp(exp2(pre)+1), pre already scaled
    const float ag = (g3 == 2) ? -2.f : 1.f;
    const float bg = (g3 == 2) ? 1.f : 0.f;

    // ---- LDS init ----
    for (int idx = t; idx < 2 * MROW * PADK; idx += 256)
        ((short*)Hst)[idx] = 0;
    for (int idx = t; idx < 2 * MROW * 52; idx += 256)
        ((float*)C1buf)[idx] = 0.f;
    __syncthreads();   // zeros before targeted writes
    if (t < MROW) {
        const int m = t;
#pragma unroll
        for (int p = 0; p < 2; ++p) {
            Hst[p][m * PADK + 156] = (short)0x3F80;   // 1.0 (bias cols)
            Hst[p][m * PADK + 157] = (short)0x3F80;
        }
        const float x0 = input[(size_t)(r0 + m) * SEQT];
        const unsigned xp = pack_hilo(x0);
        Hst[1][m * PADK + 102] = (short)xp;   // window 0 reads parity 1
        Hst[1][m * PADK + 103] = (short)(xp >> 16);
        Hst[1][m * PADK + 155] = (short)xp;
    }
    if (w == 1) {                 // prefill x chunks 0 and 1
        xchunk_fill(input, r0, 0, lane, Xbuf);
        xchunk_fill(input, r0, 1, lane, Xbuf);
    }
    float c1st[4] = {0.f, 0.f, 0.f, 0.f};
    float h3 = 0.f, c3 = 0.f;   // LSTM3 state (wave 1, lanes 0..15 valid)
    float h3b = 0.f;            // h3 broadcast across wave-1 lanes (per m)

#pragma unroll 1
    for (int ts = 0; ts <= SEQT; ++ts) {
        __syncthreads();
        const int rb = (ts + 1) & 1, wb = ts & 1;

        // ---- reads first: LDS latency overlaps the rest of the step ----
        s16x8 hf[5];
        if (ts < SEQT) {
#pragma unroll
            for (int kt = 0; kt < 5; ++kt)
                hf[kt] = *(const s16x8*)&Hst[rb][iloc * PADK + kt * 32 + kq * 8];
        }
        f32x4 c1v[13];
        if (w == 1 && ts >= 1) {
            const float* cr = &C1buf[rb][(lane & 15) * 52];
#pragma unroll
            for (int j = 0; j < 13; ++j)
                c1v[j] = *(const f32x4*)(cr + 4 * j);
        }

        // ---- coalesced dump of finished 64-chunk ----
        if (ts >= 65 && (ts & 63) == 1) {
            const int c = (ts >> 6) - 1;
#pragma unroll
            for (int rep = 0; rep < 4; ++rep) {
                const int row = w + 4 * rep;
                out[(size_t)(r0 + row) * SEQT + c * 64 + lane] =
                    Obuf[c & 1][row * OSTR + lane];
            }
        }

        // ---- x chunk prefetch: issue loads early (store at step bottom) ----
        const bool fill = (w == 1) && (ts < SEQT) && ((ts & 63) == 0) &&
                          (ts >= 64) && ((ts >> 6) < 31);
        const int fc = (ts >> 6) + 1;
        f32x4 xv[4];
        if (fill) {
            const int fm = lane & 15, fq = lane >> 4;
            const int tt = fc * 64 + fq * 16;
            if (tt < SEQT) {
                const float* src = input + (size_t)(r0 + fm) * SEQT + tt;
#pragma unroll
                for (int p = 0; p < 4; ++p) xv[p] = *(const f32x4*)(src + 4 * p);
            } else {
#pragma unroll
                for (int p = 0; p < 4; ++p) xv[p] = (f32x4){0.f, 0.f, 0.f, 0.f};
            }
        }

        if (ts < SEQT) {
            short* Hw = &Hst[wb][0];
            float* C1w = &C1buf[wb][0];
            if (w == 0) {
                run_tiles<0, 4>(Wfr, hf, c1st, Hw, C1w, iloc, kq);
            } else if (w == 2) {
                run_tiles<1, 4>(Wfr, hf, c1st, Hw, C1w, iloc, kq);
            } else if (w == 3) {
                run_tiles<2, 4>(Wfr, hf, c1st, Hw, C1w, iloc, kq);
            } else {
                // w1: x staging for step ts+1 (cols 102/103/155)
                const int t1 = ts + 1;
                if (t1 < SEQT) {
                    const int m2 = lane & 15;
                    const unsigned pv = Xbuf[(t1 >> 6) & 1][(t1 & 63) * 16 + m2];
                    *(unsigned*)&Hw[m2 * PADK + 102] = pv;
                    Hw[m2 * PADK + 155] = (short)pv;
                }
                run_tiles<3, 1>(Wfr, hf, c1st, Hw, C1w, iloc, kq);
            }
        }

        // ---- LSTM3 for step ts-1 (wave 1): dot + 64-lane activations ----
        if (w == 1 && ts >= 1) {
            float d0 = 0.f, d1 = 0.f, d2 = 0.f, d3 = 0.f;
#pragma unroll
            for (int j = 0; j < 13; ++j) {
                d0 = fmaf(Wz[4 * j + 0], c1v[j][0], d0);
                d1 = fmaf(Wz[4 * j + 1], c1v[j][1], d1);
                d2 = fmaf(Wz[4 * j + 2], c1v[j][2], d2);
                d3 = fmaf(Wz[4 * j + 3], c1v[j][3], d3);
            }
            const float z = (d0 + d1) + (d2 + d3);
            const float pre = z + fmaf(whh3g, h3b, b3g);
            const float act = bg + ag * fastrcp(EXP2F(pre) + 1.f);
            Ztr[(lane & 15) * 4 + g3] = act;
            __builtin_amdgcn_wave_barrier();   // keep write before read (1 wave)
            const int s = ts - 1;
            if (lane < MROW) {
                const f32x4 a4 = *(const f32x4*)&Ztr[lane * 4];   // i,f,g,o
                c3 = a4[1] * c3 + a4[0] * a4[2];
                h3 = a4[3] * tanhfast(c3);
                Obuf[(s >> 6) & 1][lane * OSTR + (s & 63)] = c3;
            }
            h3b = __shfl(h3, lane & 15, 64);
        }

        // ---- x chunk prefetch: pack + store (loads had the step to land) ----
        if (fill) {
            const int fm = lane & 15, fq = lane >> 4;
#pragma unroll
            for (int p = 0; p < 4; ++p)
#pragma unroll
                for (int j = 0; j < 4; ++j)
                    Xbuf[fc & 1][(fq * 16 + p * 4 + j) * 16 + fm] =
                        pack_hilo(xv[p][j]);
        }
    }

    __syncthreads();
    // tail: steps 1984..1999 (chunk 31, parity 1)
    {
        const int row = t >> 4, pos = t & 15;
        out[(size_t)(r0 + row) * SEQT + 1984 + pos] = Obuf[1][row * OSTR + pos];
    }
}

extern "C" void kernel_launch(void* const* d_in, const int* in_sizes, int n_in,
                              void* d_out, int out_size, void* d_ws, size_t ws_size,
                              hipStream_t stream) {
    const float* input = (const float*)d_in[0];
    const float* W_ih1 = (const float*)d_in[1];
    const float* W_hh1 = (const float*)d_in[2];
    const float* b_ih1 = (const float*)d_in[3];
    const float* b_hh1 = (const float*)d_in[4];
    const float* W_ih3 = (const float*)d_in[5];
    const float* W_hh3 = (const float*)d_in[6];
    const float* b_ih3 = (const float*)d_in[7];
    const float* b_hh3 = (const float*)d_in[8];
    float* out = (float*)d_out;

    lstm_fused_kernel<<<NBLK, 256, 0, stream>>>(
        input, W_ih1, W_hh1, b_ih1, b_hh1, W_ih3, W_hh3, b_ih3, b_hh3, out);
}